// Round 7
// baseline (5260.603 us; speedup 1.0000x reference)
//
#include <hip/hip_runtime.h>
#include <cfloat>

// Problem constants (fixed by setup_inputs)
#define BATCH 128
#define NP    16384
#define NC    4096
#define MPTS  (NP + NC)   // 20480
#define SOUT  2048
#define NTHR  256         // 4 waves/block = 1 wave/SIMD
#define KPT   80          // points per thread (NTHR*KPT = MPTS)
#define KPART 64          // first 64 slots come from `partial`

// One DPP max-reduce step on a u64 key split across (hi, lo) u32 regs.
// old=0 / bound_ctrl=false: invalid-source lanes contribute key 0, which is
// the identity for our max (all real keys are > 0). Byte-identical to the
// round-6 macro that passed bit-exact.
#define DPP_MAX_STEP(ctrl, rmask)                                                  \
    {                                                                              \
        unsigned int lo2 = (unsigned int)__builtin_amdgcn_update_dpp(              \
            0, (int)klo, (ctrl), (rmask), 0xF, false);                             \
        unsigned int hi2 = (unsigned int)__builtin_amdgcn_update_dpp(              \
            0, (int)khi, (ctrl), (rmask), 0xF, false);                             \
        const unsigned long long a =                                               \
            ((unsigned long long)khi << 32) | (unsigned long long)klo;             \
        const unsigned long long c =                                               \
            ((unsigned long long)hi2 << 32) | (unsigned long long)lo2;             \
        if (c > a) { klo = lo2; khi = hi2; }                                       \
    }

// One block per batch, 256 threads, 80 points/thread (m = k*256 + t), all
// coords + running min_d in registers (~350 VGPRs; waves_per_eu(1,1) gives a
// 512-VGPR budget since only 4 waves/CU ever run — grid is 128 blocks on 256
// CUs). Per step: distance update + (val,idx) argmax in registers, 6-step DPP
// wave max-reduce, 4 per-wave key slots in LDS, ONE barrier, then every
// thread redundantly picks the global max of 4 keys and reloads the winner's
// coords straight from global memory (uniform address -> broadcast; bit-exact
// same data). No atomics, no second barrier, no divergent winner-select.
__global__ __launch_bounds__(NTHR)
__attribute__((amdgpu_waves_per_eu(1, 1)))
void fps_kernel(
    const float* __restrict__ partial,   // [B, NP, 3]
    const float* __restrict__ coarse,    // [B, 3, NC]
    float* __restrict__ out)             // [B, 3, SOUT]
{
    const int b = blockIdx.x;
    const int t = threadIdx.x;
    const int wid = t >> 6;
    const int lane = t & 63;

    __shared__ unsigned long long s_keys[4];   // per-wave argmax candidates

    float x[KPT], y[KPT], z[KPT], md[KPT];

    const float* Pb = partial + (size_t)b * NP * 3;
    const float* Cb = coarse + (size_t)b * 3 * NC;

#pragma unroll
    for (int k = 0; k < KPT; ++k) {
        const int m = k * NTHR + t;
        if (k < KPART) {   // from partial ([M,3] layout)
            x[k] = Pb[m * 3 + 0];
            y[k] = Pb[m * 3 + 1];
            z[k] = Pb[m * 3 + 2];
        } else {           // from coarse ([3,NC] layout); j = m - NP
            const int j = m - NP;
            x[k] = Cb[0 * NC + j];
            y[k] = Cb[1 * NC + j];
            z[k] = Cb[2 * NC + j];
        }
        md[k] = FLT_MAX;
    }

    float* outb = out + (size_t)b * 3 * SOUT;

    // First selected index is 0: all threads read its coords (uniform addr).
    float qx = Pb[0], qy = Pb[1], qz = Pb[2];
    if (t == 0) {
        outb[0 * SOUT + 0] = qx;
        outb[1 * SOUT + 0] = qy;
        outb[2 * SOUT + 0] = qz;
    }
    // No barrier needed: s_keys is first written below, read after the
    // barrier inside the loop.

    for (int s = 0; s < SOUT - 1; ++s) {
        float bv = -1.0f;
        int bi = 0;
#pragma unroll
        for (int k = 0; k < KPT; ++k) {
            const float dx = __fsub_rn(x[k], qx);
            const float dy = __fsub_rn(y[k], qy);
            const float dz = __fsub_rn(z[k], qz);
            // Reference-exact contraction (proven bit-exact in rounds 3/6):
            // fma(dz,dz, fma(dx,dx, rn(dy*dy)))
            const float dy2 = __fmul_rn(dy, dy);
            const float d = __builtin_fmaf(dz, dz, __builtin_fmaf(dx, dx, dy2));
            const float nmd = fminf(md[k], d);
            md[k] = nmd;
            // Strict > with ascending k keeps the earliest index on ties.
            if (nmd > bv) { bv = nmd; bi = k; }
        }

        // With NTHR=256, (bi<<8)|t IS the global point index m = bi*256+t.
        // Pack (value, ~m): float bits monotone for v>=0; ~m resolves equal
        // values to the smallest global index, order-independently.
        unsigned int klo = ~((unsigned int)((bi << 8) | t));
        unsigned int khi = __float_as_uint(bv);

        // Canonical gfx9 wave64 max-reduce to lane 63 (round-6-proven):
        DPP_MAX_STEP(0x111, 0xF)  // row_shr:1
        DPP_MAX_STEP(0x112, 0xF)  // row_shr:2
        DPP_MAX_STEP(0x114, 0xF)  // row_shr:4
        DPP_MAX_STEP(0x118, 0xF)  // row_shr:8
        DPP_MAX_STEP(0x142, 0xa)  // row_bcast:15
        DPP_MAX_STEP(0x143, 0xc)  // row_bcast:31

        if (lane == 63) {
            s_keys[wid] = ((unsigned long long)khi << 32) | (unsigned long long)klo;
        }
        __syncthreads();

        // Every thread reduces the 4 wave candidates (3 u64 compares) and
        // decodes the winner's global index.
        unsigned long long wk = s_keys[0];
        const unsigned long long k1 = s_keys[1];
        const unsigned long long k2 = s_keys[2];
        const unsigned long long k3 = s_keys[3];
        if (k1 > wk) wk = k1;
        if (k2 > wk) wk = k2;
        if (k3 > wk) wk = k3;
        const unsigned int m = ~((unsigned int)wk);  // < 2^15, upper bits clear

        // Reload winner coords from global (same address on all lanes ->
        // one broadcast transaction; bit-exact same values as the owner's
        // registers). Branchless pointer select, uniform in practice.
        const int j = (int)m - NP;
        const float* ax = (m < NP) ? (Pb + (size_t)m * 3 + 0) : (Cb + 0 * NC + j);
        const float* ay = (m < NP) ? (Pb + (size_t)m * 3 + 1) : (Cb + 1 * NC + j);
        const float* az = (m < NP) ? (Pb + (size_t)m * 3 + 2) : (Cb + 2 * NC + j);
        qx = *ax; qy = *ay; qz = *az;

        if (t == 0) {
            const int slot = s + 1;
            outb[0 * SOUT + slot] = qx;
            outb[1 * SOUT + slot] = qy;
            outb[2 * SOUT + slot] = qz;
        }
        // Next iteration's s_keys writes happen only after each wave finishes
        // its ~800-instruction distance loop, long after all waves have read
        // s_keys here -- no WAR race, so no second barrier is needed.
    }
}

extern "C" void kernel_launch(void* const* d_in, const int* in_sizes, int n_in,
                              void* d_out, int out_size, void* d_ws, size_t ws_size,
                              hipStream_t stream) {
    (void)in_sizes; (void)n_in; (void)d_ws; (void)ws_size; (void)out_size;
    const float* partial = (const float*)d_in[0];
    const float* coarse  = (const float*)d_in[1];
    float* out = (float*)d_out;
    fps_kernel<<<dim3(BATCH), dim3(NTHR), 0, stream>>>(partial, coarse, out);
}